// Round 9
// baseline (149.397 us; speedup 1.0000x reference)
//
#include <hip/hip_runtime.h>
#include <math.h>

#define BB 4
#define CIN 128
#define LL 2048
#define HH 8
#define CH 32
#define HID 256

typedef __attribute__((ext_vector_type(8))) __bf16 bf16x8;
typedef __attribute__((ext_vector_type(4))) float f32x4;
typedef __attribute__((ext_vector_type(16))) float f32x16;

static __device__ __forceinline__ unsigned int f2bf(float f) {
    union { __bf16 b; unsigned short s; } u;
    u.b = (__bf16)f;
    return (unsigned int)u.s;
}
static __device__ __forceinline__ float bf2f(unsigned int s) {
    union { float f; unsigned int u; } x;
    x.u = s << 16;
    return x.f;
}

#define MFMA   __builtin_amdgcn_mfma_f32_16x16x32_bf16
#define MFMA32 __builtin_amdgcn_mfma_f32_32x32x16_bf16

// ---------------------------------------------------------------------------
// Kernel 1: QKV 1x1 conv -> bf16 buffers.
// Q: [bh][l][d] bf16, pre-scaled by log2(e)/sqrt(L) (so exp(s) == exp2(s')).
// K: [bh][l][d] bf16.  V: transposed [bh][d][l] bf16.
// ---------------------------------------------------------------------------
__global__ __launch_bounds__(256) void qkv_kernel(
        const float* __restrict__ x, const float* __restrict__ w_qkv,
        const float* __restrict__ b_qkv,
        unsigned short* __restrict__ qb, unsigned short* __restrict__ kb,
        unsigned short* __restrict__ vtb) {
    __shared__ float wl[32 * 128];
    __shared__ float tr[32 * 65];
    const int t = threadIdx.x;
    const int lt = blockIdx.x;           // 0..31
    const int g  = blockIdx.y;           // 0..23 : sel*8 + h
    const int b  = blockIdx.z;
    const int sel = g >> 3, h = g & 7;
    const int obase = sel * 256 + h * 32;
    const int l0 = lt * 64;

    const float4* wsrc = (const float4*)(w_qkv + (size_t)obase * CIN);
    float4* wdst = (float4*)wl;
    #pragma unroll
    for (int r = 0; r < 4; ++r) wdst[r * 256 + t] = wsrc[r * 256 + t];
    __syncthreads();

    const int ll = t & 63, og = t >> 6;
    float acc[8] = {0.f,0.f,0.f,0.f,0.f,0.f,0.f,0.f};
    const float* xp = x + (size_t)b * CIN * LL + l0 + ll;
    for (int i = 0; i < CIN; i += 4) {
        float x0 = xp[(size_t)(i+0) * LL];
        float x1 = xp[(size_t)(i+1) * LL];
        float x2 = xp[(size_t)(i+2) * LL];
        float x3 = xp[(size_t)(i+3) * LL];
        #pragma unroll
        for (int j = 0; j < 8; ++j) {
            float4 w4 = *(const float4*)(wl + (og * 8 + j) * 128 + i);
            acc[j] += w4.x * x0 + w4.y * x1 + w4.z * x2 + w4.w * x3;
        }
    }
    // log2(e)/sqrt(2048)
    const float scale = (sel == 0) ? 0.03187935835f : 1.0f;
    #pragma unroll
    for (int j = 0; j < 8; ++j) {
        int oc = og * 8 + j;
        tr[oc * 65 + ll] = (acc[j] + b_qkv[obase + oc]) * scale;   // [c][l]
    }
    __syncthreads();
    if (sel == 2) {
        unsigned short* dst = vtb + ((size_t)(b * HH + h) * CH) * LL + l0;
        #pragma unroll
        for (int r = 0; r < 8; ++r) {
            int flat = r * 256 + t;           // c*64 + l
            int c = flat >> 6, l = flat & 63;
            dst[(size_t)c * LL + l] = (unsigned short)f2bf(tr[c * 65 + l]);
        }
    } else {
        unsigned short* dst = (sel == 0 ? qb : kb)
                              + ((size_t)(b * HH + h) * LL + l0) * CH;
        #pragma unroll
        for (int r = 0; r < 8; ++r) {
            int flat = r * 256 + t;           // lr*32 + c
            int c = flat & 31, lr = flat >> 5;
            dst[flat] = (unsigned short)f2bf(tr[c * 65 + lr]);
        }
    }
}

// ---------------------------------------------------------------------------
// Kernel 2: softmax denominators via MFMA (K-frag prefetch pipelined), then
// scale V^T in place.  512 threads: waves 0-3 sum a in [0,1024), 4-7 the rest.
// ---------------------------------------------------------------------------
__global__ __launch_bounds__(512) void denom_mfma(
        const unsigned short* __restrict__ qb,
        const unsigned short* __restrict__ kb,
        unsigned short* __restrict__ vtb) {
    __shared__ float zz[2][64];
    const int t = threadIdx.x, wave = t >> 6, lane = t & 63;
    const int id = blockIdx.x;
    const int bh = (id & 7) * 4 + ((id >> 3) >> 5);
    const int qt = (id >> 3) & 31;
    const int ah = wave >> 2, wsub = wave & 3;
    const int q0 = qt * 64 + wsub * 16;
    const int r = lane & 15, g = lane >> 4;

    bf16x8 afrag = *(const bf16x8*)(qb + ((size_t)bh * LL + q0 + r) * CH + 8 * g);
    const unsigned short* kp = kb + ((size_t)bh * LL + ah * 1024 + r) * CH + 8 * g;

    float z0 = 0.f, z1 = 0.f, z2 = 0.f, z3 = 0.f;
    const f32x4 zero = {0.f, 0.f, 0.f, 0.f};
    bf16x8 n0 = *(const bf16x8*)(kp);
    bf16x8 n1 = *(const bf16x8*)(kp + 16 * CH);
    bf16x8 n2 = *(const bf16x8*)(kp + 32 * CH);
    bf16x8 n3 = *(const bf16x8*)(kp + 48 * CH);
    for (int it = 0; it < 16; ++it) {
        bf16x8 c0 = n0, c1 = n1, c2 = n2, c3 = n3;
        if (it < 15) {
            const unsigned short* np = kp + (size_t)(it + 1) * 64 * CH;
            n0 = *(const bf16x8*)(np);
            n1 = *(const bf16x8*)(np + 16 * CH);
            n2 = *(const bf16x8*)(np + 32 * CH);
            n3 = *(const bf16x8*)(np + 48 * CH);
        }
        f32x4 d0 = MFMA(afrag, c0, zero, 0, 0, 0);
        f32x4 d1 = MFMA(afrag, c1, zero, 0, 0, 0);
        f32x4 d2 = MFMA(afrag, c2, zero, 0, 0, 0);
        f32x4 d3 = MFMA(afrag, c3, zero, 0, 0, 0);
        z0 += __builtin_amdgcn_exp2f(d0[0]) + __builtin_amdgcn_exp2f(d1[0])
            + __builtin_amdgcn_exp2f(d2[0]) + __builtin_amdgcn_exp2f(d3[0]);
        z1 += __builtin_amdgcn_exp2f(d0[1]) + __builtin_amdgcn_exp2f(d1[1])
            + __builtin_amdgcn_exp2f(d2[1]) + __builtin_amdgcn_exp2f(d3[1]);
        z2 += __builtin_amdgcn_exp2f(d0[2]) + __builtin_amdgcn_exp2f(d1[2])
            + __builtin_amdgcn_exp2f(d2[2]) + __builtin_amdgcn_exp2f(d3[2]);
        z3 += __builtin_amdgcn_exp2f(d0[3]) + __builtin_amdgcn_exp2f(d1[3])
            + __builtin_amdgcn_exp2f(d2[3]) + __builtin_amdgcn_exp2f(d3[3]);
    }
    #pragma unroll
    for (int m = 1; m < 16; m <<= 1) {
        z0 += __shfl_xor(z0, m); z1 += __shfl_xor(z1, m);
        z2 += __shfl_xor(z2, m); z3 += __shfl_xor(z3, m);
    }
    if (r == 0) {
        *(float4*)&zz[ah][wsub * 16 + 4 * g] = make_float4(z0, z1, z2, z3);
    }
    __syncthreads();

    const int d = t >> 4, qo = (t & 15) * 4;
    const float i0 = 1.f / (zz[0][qo + 0] + zz[1][qo + 0]);
    const float i1 = 1.f / (zz[0][qo + 1] + zz[1][qo + 1]);
    const float i2 = 1.f / (zz[0][qo + 2] + zz[1][qo + 2]);
    const float i3 = 1.f / (zz[0][qo + 3] + zz[1][qo + 3]);
    unsigned short* vrow = vtb + ((size_t)bh * CH + d) * LL + qt * 64 + qo;
    uint2 v = *(const uint2*)vrow;
    unsigned int w0, w1;
    w0 = f2bf(bf2f(v.x & 0xFFFFu) * i0) | (f2bf(bf2f(v.x >> 16) * i1) << 16);
    w1 = f2bf(bf2f(v.y & 0xFFFFu) * i2) | (f2bf(bf2f(v.y >> 16) * i3) << 16);
    *(uint2*)vrow = make_uint2(w0, w1);
}

// ---------------------------------------------------------------------------
// Kernel 3: attn^T via 32x32x16 MFMA, softmax transpose FULLY IN REGISTER.
// S = MFMA(Q,K): D[q][a], col a=lane&31, 16 q-rows in regs -> reduction axis
// (q) is register-resident.  exp2 -> cvt_pk bf16 pairs -> permlane32_swap
// (lane l <-> l^32 hold same a-col) assembles the PV A-fragment (A=P^T).
// PV = MFMA(P^T, V): D[a][d].  No LDS, no lgkm waits.
// ---------------------------------------------------------------------------
__global__ __launch_bounds__(256, 4) void attn_mfma(
        const unsigned short* __restrict__ qb,
        const unsigned short* __restrict__ kb,
        const unsigned short* __restrict__ vtb,
        float* __restrict__ attnT) {
    const int t = threadIdx.x, wave = t >> 6, lane = t & 63;
    const int ln = lane & 31, hi = lane >> 5;
    const int id = blockIdx.x;                   // 0..1023
    const int rest = id >> 3;                    // 0..127
    const int bh = (id & 7) * 4 + (rest >> 5);
    const int mid = rest & 31;
    const int qh = mid & 1, at = mid >> 1;       // qh 0..1, at 0..15
    const int b = bh >> 3, h = bh & 7;
    const int a0 = at * 128 + wave * 32;
    const int q00 = qh * 1024;

    // K B-frag (loop-invariant): lane: col a=a0+ln, k=dim 8*hi+j ; kf1: dims+16
    const unsigned short* kp = kb + ((size_t)bh * LL + a0 + ln) * CH + 8 * hi;
    const bf16x8 kf0 = *(const bf16x8*)kp;
    const bf16x8 kf1 = *(const bf16x8*)(kp + 16);
    // Q A-frag: row q=q00+qi*32+ln, k=dim 8*hi+j ; +16
    const unsigned short* qp = qb + ((size_t)bh * LL + q00 + ln) * CH + 8 * hi;
    // V B-frag: col d=ln, k=q=q00+qi*32+8*hi+j ; +16
    const unsigned short* vp = vtb + ((size_t)bh * CH + ln) * LL + q00 + 8 * hi;

    f32x16 acc = {0.f,0.f,0.f,0.f,0.f,0.f,0.f,0.f,0.f,0.f,0.f,0.f,0.f,0.f,0.f,0.f};
    const f32x16 zero16 = {0.f,0.f,0.f,0.f,0.f,0.f,0.f,0.f,0.f,0.f,0.f,0.f,0.f,0.f,0.f,0.f};

#define CVTPK(dst, lo_, hi_) \
    asm("v_cvt_pk_bf16_f32 %0, %1, %2" : "=v"(dst) : "v"(lo_), "v"(hi_))
#define SWAPH(a_, b_) \
    asm("v_permlane32_swap_b32 %0, %1" : "+v"(a_), "+v"(b_))

    bf16x8 qa0 = *(const bf16x8*)(qp);
    bf16x8 qa1 = *(const bf16x8*)(qp + 16);
    bf16x8 vb0 = *(const bf16x8*)(vp);
    bf16x8 vb1 = *(const bf16x8*)(vp + 16);

#define STEP(QI, DOPF) do { \
    bf16x8 cqa0 = qa0, cqa1 = qa1, cvb0 = vb0, cvb1 = vb1; \
    if (DOPF) { \
        const unsigned short* qn = qp + (size_t)((QI) + 1) * 32 * CH; \
        qa0 = *(const bf16x8*)(qn); \
        qa1 = *(const bf16x8*)(qn + 16); \
        const unsigned short* vn = vp + ((QI) + 1) * 32; \
        vb0 = *(const bf16x8*)(vn); \
        vb1 = *(const bf16x8*)(vn + 16); \
    } \
    f32x16 s = MFMA32(cqa0, kf0, zero16, 0, 0, 0); \
    s = MFMA32(cqa1, kf1, s, 0, 0, 0); \
    float p0  = __builtin_amdgcn_exp2f(s[0]),  p1  = __builtin_amdgcn_exp2f(s[1]); \
    float p2  = __builtin_amdgcn_exp2f(s[2]),  p3  = __builtin_amdgcn_exp2f(s[3]); \
    float p4  = __builtin_amdgcn_exp2f(s[4]),  p5  = __builtin_amdgcn_exp2f(s[5]); \
    float p6  = __builtin_amdgcn_exp2f(s[6]),  p7  = __builtin_amdgcn_exp2f(s[7]); \
    float p8  = __builtin_amdgcn_exp2f(s[8]),  p9  = __builtin_amdgcn_exp2f(s[9]); \
    float p10 = __builtin_amdgcn_exp2f(s[10]), p11 = __builtin_amdgcn_exp2f(s[11]); \
    float p12 = __builtin_amdgcn_exp2f(s[12]), p13 = __builtin_amdgcn_exp2f(s[13]); \
    float p14 = __builtin_amdgcn_exp2f(s[14]), p15 = __builtin_amdgcn_exp2f(s[15]); \
    unsigned int w0, w1, w2, w3, w4, w5, w6, w7; \
    CVTPK(w0, p0,  p1);  CVTPK(w1, p2,  p3); \
    CVTPK(w2, p4,  p5);  CVTPK(w3, p6,  p7); \
    CVTPK(w4, p8,  p9);  CVTPK(w5, p10, p11); \
    CVTPK(w6, p12, p13); CVTPK(w7, p14, p15); \
    SWAPH(w0, w2); SWAPH(w1, w3); SWAPH(w4, w6); SWAPH(w5, w7); \
    union { uint4 u; bf16x8 v; } pa0, pa1; \
    pa0.u = make_uint4(w0, w1, w2, w3); \
    pa1.u = make_uint4(w4, w5, w6, w7); \
    __builtin_amdgcn_s_setprio(1); \
    acc = MFMA32(pa0.v, cvb0, acc, 0, 0, 0); \
    acc = MFMA32(pa1.v, cvb1, acc, 0, 0, 0); \
    __builtin_amdgcn_s_setprio(0); \
} while (0)

    #pragma unroll 2
    for (int qi = 0; qi < 31; ++qi) {
        STEP(qi, 1);
    }
    STEP(31, 0);

#undef STEP
#undef SWAPH
#undef CVTPK

    // D[a][d]: col d = ln, row a = (reg&3) + 8*(reg>>2) + 4*hi
    float* ob = attnT + ((size_t)qh * BB * HID + (size_t)b * HID + h * CH + ln) * LL
                + a0 + 4 * hi;
    *(f32x4*)(ob +  0) = __builtin_shufflevector(acc, acc,  0,  1,  2,  3);
    *(f32x4*)(ob +  8) = __builtin_shufflevector(acc, acc,  4,  5,  6,  7);
    *(f32x4*)(ob + 16) = __builtin_shufflevector(acc, acc,  8,  9, 10, 11);
    *(f32x4*)(ob + 24) = __builtin_shufflevector(acc, acc, 12, 13, 14, 15);
}

// ---------------------------------------------------------------------------
// Kernel 4: out[b,o,l] = BN( w_out @ (sum of 2 f32 partials) + b_out + x )
// ---------------------------------------------------------------------------
__global__ __launch_bounds__(256) void out_kernel(
        const float* __restrict__ attnT, const float* __restrict__ x,
        const float* __restrict__ w_out, const float* __restrict__ b_out,
        const float* __restrict__ bnw, const float* __restrict__ bnb,
        const float* __restrict__ bnm, const float* __restrict__ bnv,
        float* __restrict__ out) {
    __shared__ float wl[8 * 256];
    const int t = threadIdx.x;
    const int l0 = blockIdx.x * 256;
    const int o0 = blockIdx.y * 8;
    const int b  = blockIdx.z;

    const float4* ws = (const float4*)(w_out + (size_t)o0 * HID);
    float4* wd = (float4*)wl;
    #pragma unroll
    for (int r = 0; r < 2; ++r) wd[r * 256 + t] = ws[r * 256 + t];
    __syncthreads();

    float acc[8];
    #pragma unroll
    for (int j = 0; j < 8; ++j) acc[j] = 0.f;

    const size_t PART = (size_t)BB * HID * LL;   // floats per partial
    const float* ap = attnT + (size_t)b * HID * LL + l0 + t;
    for (int i = 0; i < HID; i += 4) {
        const float* p0 = ap + (size_t)(i+0) * LL;
        const float* p1 = ap + (size_t)(i+1) * LL;
        const float* p2 = ap + (size_t)(i+2) * LL;
        const float* p3 = ap + (size_t)(i+3) * LL;
        float a0 = p0[0] + p0[PART];
        float a1 = p1[0] + p1[PART];
        float a2 = p2[0] + p2[PART];
        float a3 = p3[0] + p3[PART];
        #pragma unroll
        for (int j = 0; j < 8; ++j) {
            float4 w4 = *(const float4*)(wl + j * 256 + i);
            acc[j] += w4.x * a0 + w4.y * a1 + w4.z * a2 + w4.w * a3;
        }
    }
    #pragma unroll
    for (int j = 0; j < 8; ++j) {
        const int o = o0 + j;
        const float inv = bnw[o] / sqrtf(bnv[o] + 1e-5f);
        const float sh  = bnb[o] - bnm[o] * inv;
        const size_t idx = ((size_t)b * CIN + o) * LL + l0 + t;
        float val = acc[j] + b_out[o] + x[idx];
        out[idx] = val * inv + sh;
    }
}

// ---------------------------------------------------------------------------
extern "C" void kernel_launch(void* const* d_in, const int* in_sizes, int n_in,
                              void* d_out, int out_size, void* d_ws, size_t ws_size,
                              hipStream_t stream) {
    const float* x      = (const float*)d_in[0];
    const float* w_qkv  = (const float*)d_in[1];
    const float* b_qkv  = (const float*)d_in[2];
    const float* w_out  = (const float*)d_in[3];
    const float* b_out  = (const float*)d_in[4];
    const float* bnw    = (const float*)d_in[5];
    const float* bnb    = (const float*)d_in[6];
    const float* bnm    = (const float*)d_in[7];
    const float* bnv    = (const float*)d_in[8];
    float* out = (float*)d_out;

    const size_t NBH = (size_t)BB * HH;          // 32
    const size_t QKV_ELEMS = NBH * LL * CH;      // 2,097,152 bf16 elems each
    unsigned short* qb    = (unsigned short*)d_ws;
    unsigned short* kb    = qb + QKV_ELEMS;
    unsigned short* vtb   = kb + QKV_ELEMS;
    float* attnT = (float*)(vtb + QKV_ELEMS);    // 2 x 8 MB f32 partials

    qkv_kernel<<<dim3(32, 24, BB), 256, 0, stream>>>(x, w_qkv, b_qkv, qb, kb, vtb);
    denom_mfma<<<dim3(1024), 512, 0, stream>>>(qb, kb, vtb);
    attn_mfma<<<dim3(1024), 256, 0, stream>>>(qb, kb, vtb, attnT);
    out_kernel<<<dim3(8, 16, BB), 256, 0, stream>>>(attnT, x, w_out, b_out,
                                                    bnw, bnb, bnm, bnv, out);
}

// Round 10
// 148.866 us; speedup vs baseline: 1.0036x; 1.0036x over previous
//
#include <hip/hip_runtime.h>
#include <math.h>

#define BB 4
#define CIN 128
#define LL 2048
#define HH 8
#define CH 32
#define HID 256

typedef __attribute__((ext_vector_type(8))) __bf16 bf16x8;
typedef __attribute__((ext_vector_type(4))) float f32x4;
typedef __attribute__((ext_vector_type(16))) float f32x16;

static __device__ __forceinline__ unsigned int f2bf(float f) {
    union { __bf16 b; unsigned short s; } u;
    u.b = (__bf16)f;
    return (unsigned int)u.s;
}
static __device__ __forceinline__ float bf2f(unsigned int s) {
    union { float f; unsigned int u; } x;
    x.u = s << 16;
    return x.f;
}

#define MFMA   __builtin_amdgcn_mfma_f32_16x16x32_bf16
#define MFMA32 __builtin_amdgcn_mfma_f32_32x32x16_bf16

// ---------------------------------------------------------------------------
// Kernel 1: QKV 1x1 conv -> bf16 buffers.
// Q: [bh][l][d] bf16, pre-scaled by log2(e)/sqrt(L) (so exp(s) == exp2(s')).
// K: [bh][l][d] bf16.  V: transposed [bh][d][l] bf16.
// ---------------------------------------------------------------------------
__global__ __launch_bounds__(256) void qkv_kernel(
        const float* __restrict__ x, const float* __restrict__ w_qkv,
        const float* __restrict__ b_qkv,
        unsigned short* __restrict__ qb, unsigned short* __restrict__ kb,
        unsigned short* __restrict__ vtb) {
    __shared__ float wl[32 * 128];
    __shared__ float tr[32 * 65];
    const int t = threadIdx.x;
    const int lt = blockIdx.x;           // 0..31
    const int g  = blockIdx.y;           // 0..23 : sel*8 + h
    const int b  = blockIdx.z;
    const int sel = g >> 3, h = g & 7;
    const int obase = sel * 256 + h * 32;
    const int l0 = lt * 64;

    const float4* wsrc = (const float4*)(w_qkv + (size_t)obase * CIN);
    float4* wdst = (float4*)wl;
    #pragma unroll
    for (int r = 0; r < 4; ++r) wdst[r * 256 + t] = wsrc[r * 256 + t];
    __syncthreads();

    const int ll = t & 63, og = t >> 6;
    float acc[8] = {0.f,0.f,0.f,0.f,0.f,0.f,0.f,0.f};
    const float* xp = x + (size_t)b * CIN * LL + l0 + ll;
    for (int i = 0; i < CIN; i += 4) {
        float x0 = xp[(size_t)(i+0) * LL];
        float x1 = xp[(size_t)(i+1) * LL];
        float x2 = xp[(size_t)(i+2) * LL];
        float x3 = xp[(size_t)(i+3) * LL];
        #pragma unroll
        for (int j = 0; j < 8; ++j) {
            float4 w4 = *(const float4*)(wl + (og * 8 + j) * 128 + i);
            acc[j] += w4.x * x0 + w4.y * x1 + w4.z * x2 + w4.w * x3;
        }
    }
    // log2(e)/sqrt(2048)
    const float scale = (sel == 0) ? 0.03187935835f : 1.0f;
    #pragma unroll
    for (int j = 0; j < 8; ++j) {
        int oc = og * 8 + j;
        tr[oc * 65 + ll] = (acc[j] + b_qkv[obase + oc]) * scale;   // [c][l]
    }
    __syncthreads();
    if (sel == 2) {
        unsigned short* dst = vtb + ((size_t)(b * HH + h) * CH) * LL + l0;
        #pragma unroll
        for (int r = 0; r < 8; ++r) {
            int flat = r * 256 + t;           // c*64 + l
            int c = flat >> 6, l = flat & 63;
            dst[(size_t)c * LL + l] = (unsigned short)f2bf(tr[c * 65 + l]);
        }
    } else {
        unsigned short* dst = (sel == 0 ? qb : kb)
                              + ((size_t)(b * HH + h) * LL + l0) * CH;
        #pragma unroll
        for (int r = 0; r < 8; ++r) {
            int flat = r * 256 + t;           // lr*32 + c
            int c = flat & 31, lr = flat >> 5;
            dst[flat] = (unsigned short)f2bf(tr[c * 65 + lr]);
        }
    }
}

// ---------------------------------------------------------------------------
// Kernel 2: softmax denominators via MFMA (K-frag prefetch pipelined), then
// scale V^T in place.  512 threads: waves 0-3 sum a in [0,1024), 4-7 the rest.
// ---------------------------------------------------------------------------
__global__ __launch_bounds__(512) void denom_mfma(
        const unsigned short* __restrict__ qb,
        const unsigned short* __restrict__ kb,
        unsigned short* __restrict__ vtb) {
    __shared__ float zz[2][64];
    const int t = threadIdx.x, wave = t >> 6, lane = t & 63;
    const int id = blockIdx.x;
    const int bh = (id & 7) * 4 + ((id >> 3) >> 5);
    const int qt = (id >> 3) & 31;
    const int ah = wave >> 2, wsub = wave & 3;
    const int q0 = qt * 64 + wsub * 16;
    const int r = lane & 15, g = lane >> 4;

    bf16x8 afrag = *(const bf16x8*)(qb + ((size_t)bh * LL + q0 + r) * CH + 8 * g);
    const unsigned short* kp = kb + ((size_t)bh * LL + ah * 1024 + r) * CH + 8 * g;

    float z0 = 0.f, z1 = 0.f, z2 = 0.f, z3 = 0.f;
    const f32x4 zero = {0.f, 0.f, 0.f, 0.f};
    bf16x8 n0 = *(const bf16x8*)(kp);
    bf16x8 n1 = *(const bf16x8*)(kp + 16 * CH);
    bf16x8 n2 = *(const bf16x8*)(kp + 32 * CH);
    bf16x8 n3 = *(const bf16x8*)(kp + 48 * CH);
    for (int it = 0; it < 16; ++it) {
        bf16x8 c0 = n0, c1 = n1, c2 = n2, c3 = n3;
        if (it < 15) {
            const unsigned short* np = kp + (size_t)(it + 1) * 64 * CH;
            n0 = *(const bf16x8*)(np);
            n1 = *(const bf16x8*)(np + 16 * CH);
            n2 = *(const bf16x8*)(np + 32 * CH);
            n3 = *(const bf16x8*)(np + 48 * CH);
        }
        f32x4 d0 = MFMA(afrag, c0, zero, 0, 0, 0);
        f32x4 d1 = MFMA(afrag, c1, zero, 0, 0, 0);
        f32x4 d2 = MFMA(afrag, c2, zero, 0, 0, 0);
        f32x4 d3 = MFMA(afrag, c3, zero, 0, 0, 0);
        z0 += __builtin_amdgcn_exp2f(d0[0]) + __builtin_amdgcn_exp2f(d1[0])
            + __builtin_amdgcn_exp2f(d2[0]) + __builtin_amdgcn_exp2f(d3[0]);
        z1 += __builtin_amdgcn_exp2f(d0[1]) + __builtin_amdgcn_exp2f(d1[1])
            + __builtin_amdgcn_exp2f(d2[1]) + __builtin_amdgcn_exp2f(d3[1]);
        z2 += __builtin_amdgcn_exp2f(d0[2]) + __builtin_amdgcn_exp2f(d1[2])
            + __builtin_amdgcn_exp2f(d2[2]) + __builtin_amdgcn_exp2f(d3[2]);
        z3 += __builtin_amdgcn_exp2f(d0[3]) + __builtin_amdgcn_exp2f(d1[3])
            + __builtin_amdgcn_exp2f(d2[3]) + __builtin_amdgcn_exp2f(d3[3]);
    }
    #pragma unroll
    for (int m = 1; m < 16; m <<= 1) {
        z0 += __shfl_xor(z0, m); z1 += __shfl_xor(z1, m);
        z2 += __shfl_xor(z2, m); z3 += __shfl_xor(z3, m);
    }
    if (r == 0) {
        *(float4*)&zz[ah][wsub * 16 + 4 * g] = make_float4(z0, z1, z2, z3);
    }
    __syncthreads();

    const int d = t >> 4, qo = (t & 15) * 4;
    const float i0 = 1.f / (zz[0][qo + 0] + zz[1][qo + 0]);
    const float i1 = 1.f / (zz[0][qo + 1] + zz[1][qo + 1]);
    const float i2 = 1.f / (zz[0][qo + 2] + zz[1][qo + 2]);
    const float i3 = 1.f / (zz[0][qo + 3] + zz[1][qo + 3]);
    unsigned short* vrow = vtb + ((size_t)bh * CH + d) * LL + qt * 64 + qo;
    uint2 v = *(const uint2*)vrow;
    unsigned int w0, w1;
    w0 = f2bf(bf2f(v.x & 0xFFFFu) * i0) | (f2bf(bf2f(v.x >> 16) * i1) << 16);
    w1 = f2bf(bf2f(v.y & 0xFFFFu) * i2) | (f2bf(bf2f(v.y >> 16) * i3) << 16);
    *(uint2*)vrow = make_uint2(w0, w1);
}

// ---------------------------------------------------------------------------
// Kernel 3: attn^T via 32x32x16 MFMA, in-register softmax transpose,
// SOFTWARE-PIPELINE SKEW: iteration n computes S(n+1) and consumes pw(n)
// (built last iteration), so no serial S->exp->PV chain on the critical path.
//   phase 1: prefetch q(n+2), v(n+1)
//   phase 2: S(n+1) = MFMA(q(n+1), K)
//   phase 3: PV(n) using pw(n), v(n)
//   phase 4: exp2/cvt_pk/permlane32 -> pw(n+1)
// ---------------------------------------------------------------------------
__global__ __launch_bounds__(256, 4) void attn_mfma(
        const unsigned short* __restrict__ qb,
        const unsigned short* __restrict__ kb,
        const unsigned short* __restrict__ vtb,
        float* __restrict__ attnT) {
    const int t = threadIdx.x, wave = t >> 6, lane = t & 63;
    const int ln = lane & 31, hi = lane >> 5;
    const int id = blockIdx.x;                   // 0..1023
    const int rest = id >> 3;                    // 0..127
    const int bh = (id & 7) * 4 + (rest >> 5);
    const int mid = rest & 31;
    const int qh = mid & 1, at = mid >> 1;       // qh 0..1, at 0..15
    const int b = bh >> 3, h = bh & 7;
    const int a0 = at * 128 + wave * 32;
    const int q00 = qh * 1024;

    // K B-frag (loop-invariant): lane: col a=a0+ln, k=dim 8*hi+j ; kf1: dims+16
    const unsigned short* kp = kb + ((size_t)bh * LL + a0 + ln) * CH + 8 * hi;
    const bf16x8 kf0 = *(const bf16x8*)kp;
    const bf16x8 kf1 = *(const bf16x8*)(kp + 16);
    // Q A-frag: row q=q00+qi*32+ln, k=dim 8*hi+j ; +16
    const unsigned short* qp = qb + ((size_t)bh * LL + q00 + ln) * CH + 8 * hi;
    // V B-frag: col d=ln, k=q=q00+qi*32+8*hi+j ; +16
    const unsigned short* vp = vtb + ((size_t)bh * CH + ln) * LL + q00 + 8 * hi;

    f32x16 acc = {0.f,0.f,0.f,0.f,0.f,0.f,0.f,0.f,0.f,0.f,0.f,0.f,0.f,0.f,0.f,0.f};
    const f32x16 zero16 = {0.f,0.f,0.f,0.f,0.f,0.f,0.f,0.f,0.f,0.f,0.f,0.f,0.f,0.f,0.f,0.f};

#define CVTPK(dst, lo_, hi_) \
    asm("v_cvt_pk_bf16_f32 %0, %1, %2" : "=v"(dst) : "v"(lo_), "v"(hi_))
#define SWAPH(a_, b_) \
    asm("v_permlane32_swap_b32 %0, %1" : "+v"(a_), "+v"(b_))

#define EXPPACK(sv) do { \
    float p0  = __builtin_amdgcn_exp2f((sv)[0]),  p1  = __builtin_amdgcn_exp2f((sv)[1]); \
    float p2  = __builtin_amdgcn_exp2f((sv)[2]),  p3  = __builtin_amdgcn_exp2f((sv)[3]); \
    float p4  = __builtin_amdgcn_exp2f((sv)[4]),  p5  = __builtin_amdgcn_exp2f((sv)[5]); \
    float p6  = __builtin_amdgcn_exp2f((sv)[6]),  p7  = __builtin_amdgcn_exp2f((sv)[7]); \
    float p8  = __builtin_amdgcn_exp2f((sv)[8]),  p9  = __builtin_amdgcn_exp2f((sv)[9]); \
    float p10 = __builtin_amdgcn_exp2f((sv)[10]), p11 = __builtin_amdgcn_exp2f((sv)[11]); \
    float p12 = __builtin_amdgcn_exp2f((sv)[12]), p13 = __builtin_amdgcn_exp2f((sv)[13]); \
    float p14 = __builtin_amdgcn_exp2f((sv)[14]), p15 = __builtin_amdgcn_exp2f((sv)[15]); \
    CVTPK(w0, p0,  p1);  CVTPK(w1, p2,  p3); \
    CVTPK(w2, p4,  p5);  CVTPK(w3, p6,  p7); \
    CVTPK(w4, p8,  p9);  CVTPK(w5, p10, p11); \
    CVTPK(w6, p12, p13); CVTPK(w7, p14, p15); \
    SWAPH(w0, w2); SWAPH(w1, w3); SWAPH(w4, w6); SWAPH(w5, w7); \
} while (0)

    unsigned int w0, w1, w2, w3, w4, w5, w6, w7;

    // ---- prologue: S(0) -> pw(0); load q(1), v(0) ----
    bf16x8 qa0 = *(const bf16x8*)(qp);
    bf16x8 qa1 = *(const bf16x8*)(qp + 16);
    {
        f32x16 s0v = MFMA32(qa0, kf0, zero16, 0, 0, 0);
        s0v = MFMA32(qa1, kf1, s0v, 0, 0, 0);
        EXPPACK(s0v);
    }
    qa0 = *(const bf16x8*)(qp + 32 * CH);
    qa1 = *(const bf16x8*)(qp + 32 * CH + 16);
    bf16x8 vb0 = *(const bf16x8*)(vp);
    bf16x8 vb1 = *(const bf16x8*)(vp + 16);
    const unsigned short* qpn = qp + 64 * CH;   // q frags for step n+2
    const unsigned short* vpn = vp + 32;        // v frags for step n+1

    #pragma unroll 2
    for (int n = 0; n < 31; ++n) {
        // phase 1: prefetch q(n+2), v(n+1)
        bf16x8 qf0n = *(const bf16x8*)(qpn);
        bf16x8 qf1n = *(const bf16x8*)(qpn + 16);
        qpn += 32 * CH;
        bf16x8 vb0n = *(const bf16x8*)(vpn);
        bf16x8 vb1n = *(const bf16x8*)(vpn + 16);
        vpn += 32;
        // phase 2: S(n+1)
        f32x16 s = MFMA32(qa0, kf0, zero16, 0, 0, 0);
        s = MFMA32(qa1, kf1, s, 0, 0, 0);
        // phase 3: PV(n) using pw(n) (w0..w7) and v(n)
        union { uint4 u; bf16x8 v; } pa0, pa1;
        pa0.u = make_uint4(w0, w1, w2, w3);
        pa1.u = make_uint4(w4, w5, w6, w7);
        __builtin_amdgcn_s_setprio(1);
        acc = MFMA32(pa0.v, vb0, acc, 0, 0, 0);
        acc = MFMA32(pa1.v, vb1, acc, 0, 0, 0);
        __builtin_amdgcn_s_setprio(0);
        // phase 4: pw(n+1)
        EXPPACK(s);
        // rotate
        qa0 = qf0n; qa1 = qf1n; vb0 = vb0n; vb1 = vb1n;
    }
    // epilogue: PV(31)
    {
        union { uint4 u; bf16x8 v; } pa0, pa1;
        pa0.u = make_uint4(w0, w1, w2, w3);
        pa1.u = make_uint4(w4, w5, w6, w7);
        acc = MFMA32(pa0.v, vb0, acc, 0, 0, 0);
        acc = MFMA32(pa1.v, vb1, acc, 0, 0, 0);
    }

#undef EXPPACK
#undef SWAPH
#undef CVTPK

    // D[a][d]: col d = ln, row a = (reg&3) + 8*(reg>>2) + 4*hi
    float* ob = attnT + ((size_t)qh * BB * HID + (size_t)b * HID + h * CH + ln) * LL
                + a0 + 4 * hi;
    *(f32x4*)(ob +  0) = __builtin_shufflevector(acc, acc,  0,  1,  2,  3);
    *(f32x4*)(ob +  8) = __builtin_shufflevector(acc, acc,  4,  5,  6,  7);
    *(f32x4*)(ob + 16) = __builtin_shufflevector(acc, acc,  8,  9, 10, 11);
    *(f32x4*)(ob + 24) = __builtin_shufflevector(acc, acc, 12, 13, 14, 15);
}

// ---------------------------------------------------------------------------
// Kernel 4: out[b,o,l] = BN( w_out @ (sum of 2 f32 partials) + b_out + x )
// ---------------------------------------------------------------------------
__global__ __launch_bounds__(256) void out_kernel(
        const float* __restrict__ attnT, const float* __restrict__ x,
        const float* __restrict__ w_out, const float* __restrict__ b_out,
        const float* __restrict__ bnw, const float* __restrict__ bnb,
        const float* __restrict__ bnm, const float* __restrict__ bnv,
        float* __restrict__ out) {
    __shared__ float wl[8 * 256];
    const int t = threadIdx.x;
    const int l0 = blockIdx.x * 256;
    const int o0 = blockIdx.y * 8;
    const int b  = blockIdx.z;

    const float4* ws = (const float4*)(w_out + (size_t)o0 * HID);
    float4* wd = (float4*)wl;
    #pragma unroll
    for (int r = 0; r < 2; ++r) wd[r * 256 + t] = ws[r * 256 + t];
    __syncthreads();

    float acc[8];
    #pragma unroll
    for (int j = 0; j < 8; ++j) acc[j] = 0.f;

    const size_t PART = (size_t)BB * HID * LL;   // floats per partial
    const float* ap = attnT + (size_t)b * HID * LL + l0 + t;
    for (int i = 0; i < HID; i += 4) {
        const float* p0 = ap + (size_t)(i+0) * LL;
        const float* p1 = ap + (size_t)(i+1) * LL;
        const float* p2 = ap + (size_t)(i+2) * LL;
        const float* p3 = ap + (size_t)(i+3) * LL;
        float a0 = p0[0] + p0[PART];
        float a1 = p1[0] + p1[PART];
        float a2 = p2[0] + p2[PART];
        float a3 = p3[0] + p3[PART];
        #pragma unroll
        for (int j = 0; j < 8; ++j) {
            float4 w4 = *(const float4*)(wl + j * 256 + i);
            acc[j] += w4.x * a0 + w4.y * a1 + w4.z * a2 + w4.w * a3;
        }
    }
    #pragma unroll
    for (int j = 0; j < 8; ++j) {
        const int o = o0 + j;
        const float inv = bnw[o] / sqrtf(bnv[o] + 1e-5f);
        const float sh  = bnb[o] - bnm[o] * inv;
        const size_t idx = ((size_t)b * CIN + o) * LL + l0 + t;
        float val = acc[j] + b_out[o] + x[idx];
        out[idx] = val * inv + sh;
    }
}

// ---------------------------------------------------------------------------
extern "C" void kernel_launch(void* const* d_in, const int* in_sizes, int n_in,
                              void* d_out, int out_size, void* d_ws, size_t ws_size,
                              hipStream_t stream) {
    const float* x      = (const float*)d_in[0];
    const float* w_qkv  = (const float*)d_in[1];
    const float* b_qkv  = (const float*)d_in[2];
    const float* w_out  = (const float*)d_in[3];
    const float* b_out  = (const float*)d_in[4];
    const float* bnw    = (const float*)d_in[5];
    const float* bnb    = (const float*)d_in[6];
    const float* bnm    = (const float*)d_in[7];
    const float* bnv    = (const float*)d_in[8];
    float* out = (float*)d_out;

    const size_t NBH = (size_t)BB * HH;          // 32
    const size_t QKV_ELEMS = NBH * LL * CH;      // 2,097,152 bf16 elems each
    unsigned short* qb    = (unsigned short*)d_ws;
    unsigned short* kb    = qb + QKV_ELEMS;
    unsigned short* vtb   = kb + QKV_ELEMS;
    float* attnT = (float*)(vtb + QKV_ELEMS);    // 2 x 8 MB f32 partials

    qkv_kernel<<<dim3(32, 24, BB), 256, 0, stream>>>(x, w_qkv, b_qkv, qb, kb, vtb);
    denom_mfma<<<dim3(1024), 512, 0, stream>>>(qb, kb, vtb);
    attn_mfma<<<dim3(1024), 256, 0, stream>>>(qb, kb, vtb, attnT);
    out_kernel<<<dim3(8, 16, BB), 256, 0, stream>>>(attnT, x, w_out, b_out,
                                                    bnw, bnb, bnm, bnv, out);
}